// Round 1
// baseline (1633.312 us; speedup 1.0000x reference)
//
#include <hip/hip_runtime.h>
#include <hip/hip_bf16.h>

#define N_B 32
#define M_O 20
#define C_C 512
#define S_S 196
#define S_P 208
#define K_K 3920
#define K_P 4096
#define P_G 5
#define SCALEF 0.044194173824159216f  // 1/sqrt(512)

typedef short s8v __attribute__((ext_vector_type(8)));
typedef float f4v __attribute__((ext_vector_type(4)));

__device__ __forceinline__ f4v mfma16(s8v a, s8v b, f4v c){
  return __builtin_amdgcn_mfma_f32_16x16x32_bf16(a, b, c, 0, 0, 0);
}
__device__ __forceinline__ unsigned short f2b(float x){
  __hip_bfloat16 h = __float2bfloat16(x);
  return *reinterpret_cast<unsigned short*>(&h);
}
__device__ __forceinline__ float b2f(short u){
  unsigned int v = ((unsigned int)(unsigned short)u) << 16;
  return __uint_as_float(v);
}

__global__ void k_sentinel(float* out, float v){ out[threadIdx.x] = v; }

__global__ void k_cvt(const float* __restrict__ w0, const float* __restrict__ w1,
                      const float* __restrict__ w2, const float* __restrict__ w3,
                      unsigned short* __restrict__ out){
  int i = blockIdx.x*256 + threadIdx.x;
  int m = i >> 18;
  int r = i & 262143;
  const float* s = (m==0)?w0:((m==1)?w1:((m==2)?w2:w3));
  out[i] = f2b(s[r]);
}

// Projection: per (n,m) computes Out1[s][o] = sum_c W1[o][c]*X[c][s] (+b1+pos1)
// and (DUAL) OutV[o][s] = sum_c W2[o][c]*X[c][s] (+b2+pos2), written transposed.
template<bool DUAL>
__global__ __launch_bounds__(256) void k_proj(
    const float* __restrict__ X, int Mcnt, int rowsPerN,
    const unsigned short* __restrict__ W1, const float* __restrict__ b1, const float* __restrict__ pos1,
    const unsigned short* __restrict__ W2, const float* __restrict__ b2, const float* __restrict__ pos2,
    unsigned short* __restrict__ outR, unsigned short* __restrict__ outCT)
{
  const int rb = blockIdx.x, m = blockIdx.y, n = blockIdx.z;
  const int tid = threadIdx.x, wid = tid >> 6, lane = tid & 63;
  const int lr = lane & 15, lq = lane >> 4;
  const int s0 = rb * 48;
  const int nt = (13 - rb*3) < 3 ? (13 - rb*3) : 3;
  const float* Xb = X + (size_t)(n*Mcnt + m) * (C_C * S_S);
  __shared__ unsigned short A[48][40];

  f4v accK[3][8];
  f4v accV[8][3];
  #pragma unroll
  for (int i=0;i<3;i++)
    #pragma unroll
    for (int j=0;j<8;j++){ accK[i][j]=(f4v){0,0,0,0}; accV[j][i]=(f4v){0,0,0,0}; }

  const int cl = tid >> 3;
  const int sb = (tid & 7) * 6;
  const int colbase = wid * 128;

  for (int c0 = 0; c0 < C_C; c0 += 32) {
    const float* src = Xb + (size_t)(c0 + cl) * S_S + s0;
    #pragma unroll
    for (int i = 0; i < 6; i++) {
      int s = sb + i;
      float v = (s0 + s < S_S) ? src[s] : 0.f;
      A[s][cl] = f2b(v);
    }
    __syncthreads();
    s8v af[3];
    #pragma unroll
    for (int rt = 0; rt < 3; rt++)
      if (rt < nt) af[rt] = *(const s8v*)&A[rt*16 + lr][lq*8];
    #pragma unroll
    for (int ot = 0; ot < 8; ot++) {
      int o = colbase + ot*16 + lr;
      s8v wk = *(const s8v*)(W1 + (size_t)o*C_C + c0 + lq*8);
      #pragma unroll
      for (int rt = 0; rt < 3; rt++)
        if (rt < nt) accK[rt][ot] = mfma16(af[rt], wk, accK[rt][ot]);
      if (DUAL) {
        s8v wv = *(const s8v*)(W2 + (size_t)o*C_C + c0 + lq*8);
        #pragma unroll
        for (int rt = 0; rt < 3; rt++)
          if (rt < nt) accV[ot][rt] = mfma16(wv, af[rt], accV[ot][rt]);
      }
    }
    __syncthreads();
  }

  const int lg = m / P_G;
  const int kbase = n * rowsPerN + m * S_S;
  #pragma unroll
  for (int ot = 0; ot < 8; ot++) {
    int o = colbase + ot*16 + lr;
    float bias = b1[o] + (pos1 ? pos1[lg*C_C + o] : 0.f);
    #pragma unroll
    for (int rt = 0; rt < 3; rt++) if (rt < nt) {
      #pragma unroll
      for (int r = 0; r < 4; r++) {
        int s = s0 + rt*16 + lq*4 + r;
        if (s < S_S)
          outR[(size_t)(kbase + s)*C_C + o] = f2b(accK[rt][ot][r] + bias);
      }
    }
  }
  if (DUAL) {
    unsigned short* vb = outCT + (size_t)n * C_C * K_P;
    #pragma unroll
    for (int ot = 0; ot < 8; ot++) {
      #pragma unroll
      for (int r = 0; r < 4; r++) {
        int o = colbase + ot*16 + lq*4 + r;
        float bias = b2[o] + pos2[lg*C_C + o];
        #pragma unroll
        for (int rt = 0; rt < 3; rt++) if (rt < nt) {
          int s = s0 + rt*16 + lr;
          if (s < S_S)
            vb[(size_t)o*K_P + m*S_S + s] = f2b(accV[ot][rt][r] + bias);
        }
      }
    }
  }
}

__global__ __launch_bounds__(256) void k_scores(
    const unsigned short* __restrict__ q, const unsigned short* __restrict__ kf,
    unsigned short* __restrict__ Sb)
{
  const int kb = blockIdx.x, sbk = blockIdx.y, n = blockIdx.z;
  const int tid=threadIdx.x, wid=tid>>6, lane=tid&63, lr=lane&15, lq=lane>>4;
  const int nt = (13 - sbk*3) < 3 ? (13 - sbk*3) : 3;
  const int s0 = sbk*48;
  const unsigned short* qb = q + (size_t)n*S_P*C_C;
  const unsigned short* kbp = kf + (size_t)n*K_P*C_C;
  const int kcb = kb*256 + wid*64;
  f4v acc[3][4];
  #pragma unroll
  for (int i=0;i<3;i++)
    #pragma unroll
    for (int j=0;j<4;j++) acc[i][j]=(f4v){0,0,0,0};

  for (int c0=0;c0<C_C;c0+=32){
    s8v af[3];
    #pragma unroll
    for (int rt=0;rt<3;rt++)
      if (rt<nt) af[rt] = *(const s8v*)(qb + (size_t)(s0 + rt*16 + lr)*C_C + c0 + lq*8);
    #pragma unroll
    for (int ct=0;ct<4;ct++){
      s8v bfv = *(const s8v*)(kbp + (size_t)(kcb + ct*16 + lr)*C_C + c0 + lq*8);
      #pragma unroll
      for (int rt=0;rt<3;rt++) if (rt<nt) acc[rt][ct]=mfma16(af[rt],bfv,acc[rt][ct]);
    }
  }
  #pragma unroll
  for (int ct=0;ct<4;ct++){
    int kcol = kcb + ct*16 + lr;
    if (kcol < K_K){
      #pragma unroll
      for (int rt=0;rt<3;rt++) if (rt<nt){
        #pragma unroll
        for (int r=0;r<4;r++){
          int s = s0 + rt*16 + lq*4 + r;
          Sb[((size_t)n*S_P + s)*K_P + kcol] = f2b(acc[rt][ct][r]);
        }
      }
    }
  }
}

__global__ __launch_bounds__(256) void k_softmax(unsigned short* __restrict__ Sb){
  const int row = blockIdx.x;
  const int n = row / S_S, s = row - n*S_S;
  unsigned short* p = Sb + ((size_t)n*S_P + s)*K_P;
  const int tid = threadIdx.x;
  const bool valid = tid < 245;
  float x[16];
  if (valid){
    s8v v0 = *(const s8v*)(p + tid*16);
    s8v v1 = *(const s8v*)(p + tid*16 + 8);
    #pragma unroll
    for (int i=0;i<8;i++){ x[i]=b2f(v0[i]); x[8+i]=b2f(v1[i]); }
  } else {
    #pragma unroll
    for (int i=0;i<16;i++) x[i] = -1e30f;
  }
  float mx = x[0];
  #pragma unroll
  for (int i=1;i<16;i++) mx = fmaxf(mx, x[i]);
  #pragma unroll
  for (int d=32;d>=1;d>>=1) mx = fmaxf(mx, __shfl_xor(mx, d));
  __shared__ float red1[4], red2[4];
  if ((tid&63)==0) red1[tid>>6]=mx;
  __syncthreads();
  mx = fmaxf(fmaxf(red1[0],red1[1]),fmaxf(red1[2],red1[3]));
  float sum = 0.f;
  #pragma unroll
  for (int i=0;i<16;i++){ x[i]=__expf((x[i]-mx)*SCALEF); sum+=x[i]; }
  #pragma unroll
  for (int d=32;d>=1;d>>=1) sum += __shfl_xor(sum, d);
  if ((tid&63)==0) red2[tid>>6]=sum;
  __syncthreads();
  sum = red2[0]+red2[1]+red2[2]+red2[3];
  float inv = 1.f/sum;
  unsigned short o16[16];
  #pragma unroll
  for (int i=0;i<16;i++) o16[i] = f2b(x[i]*inv);
  *(s8v*)(p + tid*16) = *(const s8v*)o16;
  *(s8v*)(p + tid*16 + 8) = *(const s8v*)(o16+8);
}

__global__ __launch_bounds__(256) void k_pv(const unsigned short* __restrict__ Pb,
    const unsigned short* __restrict__ vt, float* __restrict__ O)
{
  const int cb=blockIdx.x, sbk=blockIdx.y, n=blockIdx.z;
  const int tid=threadIdx.x, wid=tid>>6, lane=tid&63, lr=lane&15, lq=lane>>4;
  const int nt = (13 - sbk*3) < 3 ? (13 - sbk*3) : 3;
  const int s0 = sbk*48;
  const unsigned short* pb = Pb + (size_t)n*S_P*K_P;
  const unsigned short* vb = vt + (size_t)n*C_C*K_P;
  const int ccb = cb*256 + wid*64;
  f4v acc[3][4];
  #pragma unroll
  for (int i=0;i<3;i++)
    #pragma unroll
    for (int j=0;j<4;j++) acc[i][j]=(f4v){0,0,0,0};

  for (int k0=0;k0<K_P;k0+=32){
    s8v af[3];
    #pragma unroll
    for (int rt=0;rt<3;rt++)
      if (rt<nt) af[rt] = *(const s8v*)(pb + (size_t)(s0+rt*16+lr)*K_P + k0 + lq*8);
    #pragma unroll
    for (int ct=0;ct<4;ct++){
      s8v bfv = *(const s8v*)(vb + (size_t)(ccb+ct*16+lr)*K_P + k0 + lq*8);
      #pragma unroll
      for (int rt=0;rt<3;rt++) if (rt<nt) acc[rt][ct]=mfma16(af[rt],bfv,acc[rt][ct]);
    }
  }
  #pragma unroll
  for (int ct=0;ct<4;ct++){
    #pragma unroll
    for (int rt=0;rt<3;rt++) if (rt<nt){
      #pragma unroll
      for (int r=0;r<4;r++){
        int s = s0+rt*16+lq*4+r;
        O[((size_t)n*S_P + s)*C_C + ccb + ct*16 + lr] = acc[rt][ct][r];
      }
    }
  }
}

__global__ void k_lnpart(const float* __restrict__ O, float* __restrict__ sums){
  const int part = blockIdx.x, n = blockIdx.y;
  const int tid = threadIdx.x;
  const float* base = O + ((size_t)n*S_P + part*49)*C_C;
  float ls=0.f, ls2=0.f;
  for (int i = tid; i < 49*C_C/4; i += 256){
    f4v v = ((const f4v*)base)[i];
    ls  += v[0]+v[1]+v[2]+v[3];
    ls2 += v[0]*v[0]+v[1]*v[1]+v[2]*v[2]+v[3]*v[3];
  }
  #pragma unroll
  for (int d=32;d>=1;d>>=1){ ls += __shfl_xor(ls,d); ls2 += __shfl_xor(ls2,d); }
  __shared__ float r1[4], r2[4];
  if ((tid&63)==0){ r1[tid>>6]=ls; r2[tid>>6]=ls2; }
  __syncthreads();
  if (tid==0){
    atomicAdd(&sums[n*2],   r1[0]+r1[1]+r1[2]+r1[3]);
    atomicAdd(&sums[n*2+1], r2[0]+r2[1]+r2[2]+r2[3]);
  }
}

__global__ void k_norm(const float* __restrict__ O, const float* __restrict__ sums,
                       unsigned short* __restrict__ ob){
  size_t g = (size_t)blockIdx.x*256 + threadIdx.x;
  int n = (int)(g / (S_P*C_C/8));
  int rem = (int)(g - (size_t)n*(S_P*C_C/8));
  int s = rem / (C_C/8);
  const float inv = 1.f/((float)S_S*C_C);
  float mu = sums[n*2]*inv;
  float var = sums[n*2+1]*inv - mu*mu;
  float rq = rsqrtf(var + 1e-5f);
  const f4v* src = (const f4v*)(O + g*8);
  f4v a = src[0], b = src[1];
  unsigned short o16[8];
  if (s < S_S){
    #pragma unroll
    for (int i=0;i<4;i++){ float y=(a[i]-mu)*rq; o16[i]=f2b(fmaxf(y,0.f)); }
    #pragma unroll
    for (int i=0;i<4;i++){ float y=(b[i]-mu)*rq; o16[4+i]=f2b(fmaxf(y,0.f)); }
  } else {
    #pragma unroll
    for (int i=0;i<8;i++) o16[i]=0;
  }
  *(s8v*)(ob + g*8) = *(const s8v*)o16;
}

__global__ __launch_bounds__(256) void k_final(const unsigned short* __restrict__ ob,
    const unsigned short* __restrict__ Wo, const float* __restrict__ bo,
    const float* __restrict__ person, float* __restrict__ out)
{
  const int ocb = blockIdx.x, n = blockIdx.y;
  const int tid=threadIdx.x, wid=tid>>6, lane=tid&63, lr=lane&15, lq=lane>>4;
  const int ocb0 = ocb*64 + wid*16;
  const unsigned short* obp = ob + (size_t)n*S_P*C_C;
  f4v acc[13];
  #pragma unroll
  for (int i=0;i<13;i++) acc[i]=(f4v){0,0,0,0};
  for (int c0=0;c0<C_C;c0+=32){
    s8v af = *(const s8v*)(Wo + (size_t)(ocb0+lr)*C_C + c0 + lq*8);
    #pragma unroll
    for (int ct=0;ct<13;ct++){
      s8v bfv = *(const s8v*)(obp + (size_t)(ct*16+lr)*C_C + c0 + lq*8);
      acc[ct]=mfma16(af,bfv,acc[ct]);
    }
  }
  #pragma unroll
  for (int ct=0;ct<13;ct++){
    #pragma unroll
    for (int r=0;r<4;r++){
      int oc = ocb0 + lq*4 + r;
      int s = ct*16 + lr;
      if (s < S_S){
        size_t idx = ((size_t)n*C_C + oc)*S_S + s;
        out[idx] = acc[ct][r] + bo[oc] + person[idx];
      }
    }
  }
}

extern "C" void kernel_launch(void* const* d_in, const int* in_sizes, int n_in,
                              void* d_out, int out_size, void* d_ws, size_t ws_size,
                              hipStream_t stream)
{
  (void)in_sizes; (void)n_in; (void)out_size;
  const float* person = (const float*)d_in[0];
  const float* others = (const float*)d_in[1];
  const float* Wq = (const float*)d_in[2];
  const float* bq = (const float*)d_in[3];
  const float* Wk = (const float*)d_in[4];
  const float* bk = (const float*)d_in[5];
  const float* Wv = (const float*)d_in[6];
  const float* bv = (const float*)d_in[7];
  const float* Wo = (const float*)d_in[8];
  const float* bo = (const float*)d_in[9];
  const float* pos_k = (const float*)d_in[10];
  const float* pos_v = (const float*)d_in[11];
  float* out = (float*)d_out;

  char* ws = (char*)d_ws;
  size_t off = 0;
  auto alloc = [&](size_t bytes)->char*{
    char* p = ws + off; off += (bytes + 255) & ~(size_t)255; return p;
  };
  unsigned short* Wb   = (unsigned short*)alloc(4ull*C_C*C_C*2);
  unsigned short* qb   = (unsigned short*)alloc((size_t)N_B*S_P*C_C*2);
  unsigned short* kfb  = (unsigned short*)alloc((size_t)N_B*K_P*C_C*2);
  unsigned short* vtb  = (unsigned short*)alloc((size_t)N_B*C_C*K_P*2);
  unsigned short* Sbuf = (unsigned short*)alloc((size_t)N_B*S_P*K_P*2);
  float* Obuf          = (float*)alloc((size_t)N_B*S_P*C_C*4);
  unsigned short* obb  = (unsigned short*)alloc((size_t)N_B*S_P*C_C*2);
  float* sums          = (float*)alloc(2*N_B*sizeof(float));

  if (off > ws_size) {
    k_sentinel<<<1,256,0,stream>>>(out, (float)(ws_size>>20));
    return;
  }

  hipMemsetAsync(sums, 0, 2*N_B*sizeof(float), stream);
  k_cvt<<<4096,256,0,stream>>>(Wq,Wk,Wv,Wo,Wb);
  k_proj<true ><<<dim3(5,M_O,N_B),256,0,stream>>>(others, M_O, K_P,
      Wb + 262144, bk, pos_k, Wb + 2*262144, bv, pos_v, kfb, vtb);
  k_proj<false><<<dim3(5,1,N_B),256,0,stream>>>(person, 1, S_P,
      Wb, bq, nullptr, nullptr, nullptr, nullptr, qb, nullptr);
  k_scores<<<dim3(16,5,N_B),256,0,stream>>>(qb, kfb, Sbuf);
  k_softmax<<<N_B*S_S,256,0,stream>>>(Sbuf);
  k_pv<<<dim3(2,5,N_B),256,0,stream>>>(Sbuf, vtb, Obuf);
  k_lnpart<<<dim3(4,N_B),256,0,stream>>>(Obuf, sums);
  k_norm<<<1664,256,0,stream>>>(Obuf, sums, obb);
  k_final<<<dim3(8,N_B),256,0,stream>>>(obb, Wb + 3*262144, bo, person, out);
}

// Round 2
// 1304.145 us; speedup vs baseline: 1.2524x; 1.2524x over previous
//
#include <hip/hip_runtime.h>
#include <hip/hip_bf16.h>

#define N_B 32
#define M_O 20
#define C_C 512
#define S_S 196
#define S_P 208
#define K_K 3920
#define K_P 4096
#define P_G 5
#define SCALEF 0.044194173824159216f  // 1/sqrt(512)

typedef short s4v __attribute__((ext_vector_type(4)));
typedef short s8v __attribute__((ext_vector_type(8)));
typedef float f4v __attribute__((ext_vector_type(4)));

__device__ __forceinline__ f4v mfma16(s8v a, s8v b, f4v c){
  return __builtin_amdgcn_mfma_f32_16x16x32_bf16(a, b, c, 0, 0, 0);
}
__device__ __forceinline__ unsigned short f2b(float x){
  __hip_bfloat16 h = __float2bfloat16(x);
  return *reinterpret_cast<unsigned short*>(&h);
}
__device__ __forceinline__ float b2f(short u){
  unsigned int v = ((unsigned int)(unsigned short)u) << 16;
  return __uint_as_float(v);
}

__global__ void k_sentinel(float* out, float v){ out[threadIdx.x] = v; }

// fp32 -> bf16 weight conversion, vectorized (4 mats of 512x512, contiguous out)
__global__ void k_cvt(const float* __restrict__ w0, const float* __restrict__ w1,
                      const float* __restrict__ w2, const float* __restrict__ w3,
                      unsigned short* __restrict__ out){
  int i = blockIdx.x*256 + threadIdx.x;   // f4 index; 4*65536 total
  int m = i >> 16;
  int r = i & 65535;
  const float* s = (m==0)?w0:((m==1)?w1:((m==2)?w2:w3));
  f4v v = ((const f4v*)s)[r];
  s4v o = { (short)f2b(v[0]), (short)f2b(v[1]), (short)f2b(v[2]), (short)f2b(v[3]) };
  ((s4v*)out)[i] = o;
}

// Transpose+cvt: X fp32 [slab][512][196] -> Xt bf16 [slab][196][512]
// grid (8 c-chunks of 64, slabs), 256 threads
__global__ __launch_bounds__(256) void k_tr(const float* __restrict__ X,
                                            unsigned short* __restrict__ Xt){
  const int cc = blockIdx.x * 64;
  const int slab = blockIdx.y;
  const int tid = threadIdx.x;
  __shared__ unsigned short A[196][72];   // pad 72: conflict-free b128 reads
  const int row = tid >> 2;               // 0..63 (c within chunk)
  const int j   = tid & 3;
  const float* src = X + (size_t)slab*(C_C*S_S) + (size_t)(cc+row)*S_S;
  for (int p = j; p < 49; p += 4){
    f4v v = *(const f4v*)(src + p*4);
    int s = p*4;
    A[s+0][row] = f2b(v[0]);
    A[s+1][row] = f2b(v[1]);
    A[s+2][row] = f2b(v[2]);
    A[s+3][row] = f2b(v[3]);
  }
  __syncthreads();
  unsigned short* dst = Xt + (size_t)slab*(S_S*C_C) + cc;
  for (int v = tid; v < S_S*8; v += 256){
    int s = v >> 3, c8 = v & 7;
    *(s8v*)(dst + (size_t)s*C_C + c8*8) = *(const s8v*)&A[s][c8*8];
  }
}

// Barrier-free projection GEMM.
// Xt bf16 [slab=(n,m)][196][512]. Per wave: 64 K-cols and (HASV) 64 V-cols.
// outK[n][Mcnt*196][512] row-major; outVT[n][512][K_P] (V transposed).
// grid (colhalf 2, rowtile 5, slab), 256 threads
template<bool HASV>
__global__ __launch_bounds__(256) void k_projgemm(
    const unsigned short* __restrict__ Xt, int Mcnt,
    const unsigned short* __restrict__ W1, const float* __restrict__ b1, const float* __restrict__ pos1,
    const unsigned short* __restrict__ W2, const float* __restrict__ b2, const float* __restrict__ pos2,
    unsigned short* __restrict__ outK, unsigned short* __restrict__ outVT)
{
  const int ch = blockIdx.x, rb = blockIdx.y, slab = blockIdx.z;
  const int n = slab / Mcnt, m = slab - n*Mcnt;
  const int tid = threadIdx.x, wid = tid>>6, lane = tid&63;
  const int lr = lane&15, lq = lane>>4;
  const int s0 = rb*48;
  const int nt3 = 13 - rb*3; const int nt = nt3 < 3 ? nt3 : 3;
  const unsigned short* Xs = Xt + (size_t)slab*(S_S*C_C);
  const int cb = ch*256 + wid*64;

  f4v accK[3][4], accV[4][3];
  #pragma unroll
  for (int i=0;i<3;i++)
    #pragma unroll
    for (int j=0;j<4;j++){ accK[i][j]=(f4v){0,0,0,0}; accV[j][i]=(f4v){0,0,0,0}; }

  for (int c0=0;c0<C_C;c0+=32){
    s8v af[3];
    #pragma unroll
    for (int rt=0;rt<3;rt++)
      if (rt<nt) af[rt] = *(const s8v*)(Xs + (size_t)(s0+rt*16+lr)*C_C + c0 + lq*8);
    #pragma unroll
    for (int ot=0;ot<4;ot++){
      s8v wk = *(const s8v*)(W1 + (size_t)(cb+ot*16+lr)*C_C + c0 + lq*8);
      #pragma unroll
      for (int rt=0;rt<3;rt++)
        if (rt<nt) accK[rt][ot] = mfma16(af[rt], wk, accK[rt][ot]);
      if (HASV){
        s8v wv = *(const s8v*)(W2 + (size_t)(cb+ot*16+lr)*C_C + c0 + lq*8);
        #pragma unroll
        for (int rt=0;rt<3;rt++)
          if (rt<nt) accV[ot][rt] = mfma16(wv, af[rt], accV[ot][rt]);
      }
    }
  }

  const int lg = m / P_G;
  unsigned short* kout = outK + (size_t)(n*Mcnt + m)*S_S*C_C;
  #pragma unroll
  for (int ot=0;ot<4;ot++){
    int o = cb + ot*16 + lr;
    float bias = b1[o] + (pos1 ? pos1[lg*C_C+o] : 0.f);
    #pragma unroll
    for (int rt=0;rt<3;rt++) if (rt<nt){
      #pragma unroll
      for (int r=0;r<4;r++){
        int s = s0 + rt*16 + lq*4 + r;
        if (s < S_S) kout[(size_t)s*C_C + o] = f2b(accK[rt][ot][r] + bias);
      }
    }
  }
  if (HASV){
    unsigned short* vb = outVT + (size_t)n*C_C*K_P + (size_t)m*S_S;
    #pragma unroll
    for (int ot=0;ot<4;ot++){
      #pragma unroll
      for (int r=0;r<4;r++){
        int o = cb + ot*16 + lq*4 + r;
        float bias = b2[o] + pos2[lg*C_C+o];
        #pragma unroll
        for (int rt=0;rt<3;rt++) if (rt<nt){
          int s = s0 + rt*16 + lr;
          if (s < S_S) vb[(size_t)o*K_P + s] = f2b(accV[ot][rt][r] + bias);
        }
      }
    }
  }
}

// QK^T: q [n][196][512], kf [n][3920][512] -> Sb bf16 [n][208][4096] (0 for k>=3920)
__global__ __launch_bounds__(256) void k_scores(
    const unsigned short* __restrict__ q, const unsigned short* __restrict__ kf,
    unsigned short* __restrict__ Sb)
{
  const int kb = blockIdx.x, sbk = blockIdx.y, n = blockIdx.z;
  const int tid=threadIdx.x, wid=tid>>6, lane=tid&63, lr=lane&15, lq=lane>>4;
  const int nt3 = 13 - sbk*3; const int nt = nt3 < 3 ? nt3 : 3;
  const int s0 = sbk*48;
  const unsigned short* qb = q + (size_t)n*S_S*C_C;
  const unsigned short* kbp = kf + (size_t)n*K_K*C_C;
  const int kcb = kb*256 + wid*64;
  f4v acc[3][4];
  #pragma unroll
  for (int i=0;i<3;i++)
    #pragma unroll
    for (int j=0;j<4;j++) acc[i][j]=(f4v){0,0,0,0};

  for (int c0=0;c0<C_C;c0+=32){
    s8v af[3];
    #pragma unroll
    for (int rt=0;rt<3;rt++)
      if (rt<nt) af[rt] = *(const s8v*)(qb + (size_t)(s0 + rt*16 + lr)*C_C + c0 + lq*8);
    #pragma unroll
    for (int ct=0;ct<4;ct++){
      s8v bfv = *(const s8v*)(kbp + (size_t)(kcb + ct*16 + lr)*C_C + c0 + lq*8);
      #pragma unroll
      for (int rt=0;rt<3;rt++) if (rt<nt) acc[rt][ct]=mfma16(af[rt],bfv,acc[rt][ct]);
    }
  }
  #pragma unroll
  for (int ct=0;ct<4;ct++){
    int kcol = kcb + ct*16 + lr;
    #pragma unroll
    for (int rt=0;rt<3;rt++) if (rt<nt){
      #pragma unroll
      for (int r=0;r<4;r++){
        int s = s0 + rt*16 + lq*4 + r;
        Sb[((size_t)n*S_P + s)*K_P + kcol] = (kcol < K_K) ? f2b(acc[rt][ct][r]) : (unsigned short)0;
      }
    }
  }
}

__global__ __launch_bounds__(256) void k_softmax(unsigned short* __restrict__ Sb){
  const int row = blockIdx.x;
  const int n = row / S_S, s = row - n*S_S;
  unsigned short* p = Sb + ((size_t)n*S_P + s)*K_P;
  const int tid = threadIdx.x;
  const bool valid = tid < 245;
  float x[16];
  if (valid){
    s8v v0 = *(const s8v*)(p + tid*16);
    s8v v1 = *(const s8v*)(p + tid*16 + 8);
    #pragma unroll
    for (int i=0;i<8;i++){ x[i]=b2f(v0[i]); x[8+i]=b2f(v1[i]); }
  } else {
    #pragma unroll
    for (int i=0;i<16;i++) x[i] = -1e30f;
  }
  float mx = x[0];
  #pragma unroll
  for (int i=1;i<16;i++) mx = fmaxf(mx, x[i]);
  #pragma unroll
  for (int d=32;d>=1;d>>=1) mx = fmaxf(mx, __shfl_xor(mx, d));
  __shared__ float red1[4], red2[4];
  if ((tid&63)==0) red1[tid>>6]=mx;
  __syncthreads();
  mx = fmaxf(fmaxf(red1[0],red1[1]),fmaxf(red1[2],red1[3]));
  float sum = 0.f;
  #pragma unroll
  for (int i=0;i<16;i++){ x[i]=__expf((x[i]-mx)*SCALEF); sum+=x[i]; }
  #pragma unroll
  for (int d=32;d>=1;d>>=1) sum += __shfl_xor(sum, d);
  if ((tid&63)==0) red2[tid>>6]=sum;
  __syncthreads();
  sum = red2[0]+red2[1]+red2[2]+red2[3];
  float inv = 1.f/sum;
  unsigned short o16[16];
  #pragma unroll
  for (int i=0;i<16;i++) o16[i] = f2b(x[i]*inv);
  if (valid){
    *(s8v*)(p + tid*16) = *(const s8v*)o16;
    *(s8v*)(p + tid*16 + 8) = *(const s8v*)(o16+8);
  }
}

__global__ __launch_bounds__(256) void k_pv(const unsigned short* __restrict__ Pb,
    const unsigned short* __restrict__ vt, float* __restrict__ O)
{
  const int cbk=blockIdx.x, sbk=blockIdx.y, n=blockIdx.z;
  const int tid=threadIdx.x, wid=tid>>6, lane=tid&63, lr=lane&15, lq=lane>>4;
  const int nt3 = 13 - sbk*3; const int nt = nt3 < 3 ? nt3 : 3;
  const int s0 = sbk*48;
  const unsigned short* pb = Pb + (size_t)n*S_P*K_P;
  const unsigned short* vb = vt + (size_t)n*C_C*K_P;
  const int ccb = cbk*256 + wid*64;
  f4v acc[3][4];
  #pragma unroll
  for (int i=0;i<3;i++)
    #pragma unroll
    for (int j=0;j<4;j++) acc[i][j]=(f4v){0,0,0,0};

  for (int k0=0;k0<K_P;k0+=32){
    s8v af[3];
    #pragma unroll
    for (int rt=0;rt<3;rt++)
      if (rt<nt) af[rt] = *(const s8v*)(pb + (size_t)(s0+rt*16+lr)*K_P + k0 + lq*8);
    #pragma unroll
    for (int ct=0;ct<4;ct++){
      s8v bfv = *(const s8v*)(vb + (size_t)(ccb+ct*16+lr)*K_P + k0 + lq*8);
      #pragma unroll
      for (int rt=0;rt<3;rt++) if (rt<nt) acc[rt][ct]=mfma16(af[rt],bfv,acc[rt][ct]);
    }
  }
  #pragma unroll
  for (int ct=0;ct<4;ct++){
    #pragma unroll
    for (int rt=0;rt<3;rt++) if (rt<nt){
      #pragma unroll
      for (int r=0;r<4;r++){
        int s = s0+rt*16+lq*4+r;
        O[((size_t)n*S_P + s)*C_C + ccb + ct*16 + lr] = acc[rt][ct][r];
      }
    }
  }
}

__global__ void k_lnpart(const float* __restrict__ O, float* __restrict__ sums){
  const int part = blockIdx.x, n = blockIdx.y;
  const int tid = threadIdx.x;
  const float* base = O + ((size_t)n*S_P + part*49)*C_C;
  float ls=0.f, ls2=0.f;
  for (int i = tid; i < 49*C_C/4; i += 256){
    f4v v = ((const f4v*)base)[i];
    ls  += v[0]+v[1]+v[2]+v[3];
    ls2 += v[0]*v[0]+v[1]*v[1]+v[2]*v[2]+v[3]*v[3];
  }
  #pragma unroll
  for (int d=32;d>=1;d>>=1){ ls += __shfl_xor(ls,d); ls2 += __shfl_xor(ls2,d); }
  __shared__ float r1[4], r2[4];
  if ((tid&63)==0){ r1[tid>>6]=ls; r2[tid>>6]=ls2; }
  __syncthreads();
  if (tid==0){
    atomicAdd(&sums[n*2],   r1[0]+r1[1]+r1[2]+r1[3]);
    atomicAdd(&sums[n*2+1], r2[0]+r2[1]+r2[2]+r2[3]);
  }
}

__global__ void k_norm(const float* __restrict__ O, const float* __restrict__ sums,
                       unsigned short* __restrict__ ob){
  size_t g = (size_t)blockIdx.x*256 + threadIdx.x;
  int n = (int)(g / (S_P*C_C/8));
  int rem = (int)(g - (size_t)n*(S_P*C_C/8));
  int s = rem / (C_C/8);
  const float inv = 1.f/((float)S_S*C_C);
  float mu = sums[n*2]*inv;
  float var = sums[n*2+1]*inv - mu*mu;
  float rq = rsqrtf(var + 1e-5f);
  const f4v* src = (const f4v*)(O + g*8);
  f4v a = src[0], b = src[1];
  unsigned short o16[8];
  if (s < S_S){
    #pragma unroll
    for (int i=0;i<4;i++){ float y=(a[i]-mu)*rq; o16[i]=f2b(fmaxf(y,0.f)); }
    #pragma unroll
    for (int i=0;i<4;i++){ float y=(b[i]-mu)*rq; o16[4+i]=f2b(fmaxf(y,0.f)); }
  } else {
    #pragma unroll
    for (int i=0;i<8;i++) o16[i]=0;
  }
  *(s8v*)(ob + g*8) = *(const s8v*)o16;
}

__global__ __launch_bounds__(256) void k_final(const unsigned short* __restrict__ ob,
    const unsigned short* __restrict__ Wo, const float* __restrict__ bo,
    const float* __restrict__ person, float* __restrict__ out)
{
  const int ocb = blockIdx.x, n = blockIdx.y;
  const int tid=threadIdx.x, wid=tid>>6, lane=tid&63, lr=lane&15, lq=lane>>4;
  const int ocb0 = ocb*64 + wid*16;
  const unsigned short* obp = ob + (size_t)n*S_P*C_C;
  f4v acc[13];
  #pragma unroll
  for (int i=0;i<13;i++) acc[i]=(f4v){0,0,0,0};
  for (int c0=0;c0<C_C;c0+=32){
    s8v af = *(const s8v*)(Wo + (size_t)(ocb0+lr)*C_C + c0 + lq*8);
    #pragma unroll
    for (int ct=0;ct<13;ct++){
      s8v bfv = *(const s8v*)(obp + (size_t)(ct*16+lr)*C_C + c0 + lq*8);
      acc[ct]=mfma16(af,bfv,acc[ct]);
    }
  }
  #pragma unroll
  for (int ct=0;ct<13;ct++){
    #pragma unroll
    for (int r=0;r<4;r++){
      int oc = ocb0 + lq*4 + r;
      int s = ct*16 + lr;
      if (s < S_S){
        size_t idx = ((size_t)n*C_C + oc)*S_S + s;
        out[idx] = acc[ct][r] + bo[oc] + person[idx];
      }
    }
  }
}

extern "C" void kernel_launch(void* const* d_in, const int* in_sizes, int n_in,
                              void* d_out, int out_size, void* d_ws, size_t ws_size,
                              hipStream_t stream)
{
  (void)in_sizes; (void)n_in; (void)out_size;
  const float* person = (const float*)d_in[0];
  const float* others = (const float*)d_in[1];
  const float* Wq = (const float*)d_in[2];
  const float* bq = (const float*)d_in[3];
  const float* Wk = (const float*)d_in[4];
  const float* bk = (const float*)d_in[5];
  const float* Wv = (const float*)d_in[6];
  const float* bv = (const float*)d_in[7];
  const float* Wo = (const float*)d_in[8];
  const float* bo = (const float*)d_in[9];
  const float* pos_k = (const float*)d_in[10];
  const float* pos_v = (const float*)d_in[11];
  float* out = (float*)d_out;

  char* ws = (char*)d_ws;
  size_t off = 0;
  auto alloc = [&](size_t bytes)->char*{
    char* p = ws + off; off += (bytes + 255) & ~(size_t)255; return p;
  };
  unsigned short* Wb  = (unsigned short*)alloc(4ull*C_C*C_C*2);
  unsigned short* Xt  = (unsigned short*)alloc(((size_t)N_B*M_O*S_S + 16)*C_C*2);
  unsigned short* Qt  = (unsigned short*)alloc(((size_t)N_B*S_S + 16)*C_C*2);
  unsigned short* qb  = (unsigned short*)alloc(((size_t)N_B*S_S + 16)*C_C*2);
  unsigned short* kfb = (unsigned short*)alloc(((size_t)N_B*K_K + 256)*C_C*2);
  unsigned short* vtb = (unsigned short*)alloc((size_t)N_B*C_C*K_P*2);
  float* sums         = (float*)alloc(2*N_B*sizeof(float));

  // alias dead Xt region for post-projection buffers
  size_t aoff = 0;
  auto alias = [&](size_t bytes)->char*{
    char* p = (char*)Xt + aoff; aoff += (bytes + 255) & ~(size_t)255; return p;
  };
  unsigned short* Sbuf = (unsigned short*)alias((size_t)N_B*S_P*K_P*2);
  float* Obuf          = (float*)alias((size_t)N_B*S_P*C_C*4);
  unsigned short* obb  = (unsigned short*)alias((size_t)N_B*S_P*C_C*2);

  if (off > ws_size) {
    k_sentinel<<<1,256,0,stream>>>(out, (float)(ws_size>>20));
    return;
  }

  hipMemsetAsync(sums, 0, 2*N_B*sizeof(float), stream);
  k_cvt<<<1024,256,0,stream>>>(Wq,Wk,Wv,Wo,Wb);
  k_tr<<<dim3(8,N_B*M_O),256,0,stream>>>(others, Xt);
  k_tr<<<dim3(8,N_B),256,0,stream>>>(person, Qt);
  k_projgemm<true ><<<dim3(2,5,N_B*M_O),256,0,stream>>>(Xt, M_O,
      Wb + 262144, bk, pos_k, Wb + 2*262144, bv, pos_v, kfb, vtb);
  k_projgemm<false><<<dim3(2,5,N_B),256,0,stream>>>(Qt, 1,
      Wb, bq, nullptr, nullptr, nullptr, nullptr, qb, nullptr);
  k_scores<<<dim3(16,5,N_B),256,0,stream>>>(qb, kfb, Sbuf);
  k_softmax<<<N_B*S_S,256,0,stream>>>(Sbuf);
  k_pv<<<dim3(2,5,N_B),256,0,stream>>>(Sbuf, vtb, Obuf);
  k_lnpart<<<dim3(4,N_B),256,0,stream>>>(Obuf, sums);
  k_norm<<<1664,256,0,stream>>>(Obuf, sums, obb);
  k_final<<<dim3(8,N_B),256,0,stream>>>(obb, Wb + 3*262144, bo, person, out);
}

// Round 3
// 1090.742 us; speedup vs baseline: 1.4974x; 1.1956x over previous
//
#include <hip/hip_runtime.h>
#include <hip/hip_bf16.h>

#define N_B 32
#define M_O 20
#define C_C 512
#define S_S 196
#define S_P 208
#define K_K 3920
#define K_P 4096
#define P_G 5
#define SCALEF 0.044194173824159216f  // 1/sqrt(512)

typedef short s4v __attribute__((ext_vector_type(4)));
typedef short s8v __attribute__((ext_vector_type(8)));
typedef float f4v __attribute__((ext_vector_type(4)));

__device__ __forceinline__ f4v mfma16(s8v a, s8v b, f4v c){
  return __builtin_amdgcn_mfma_f32_16x16x32_bf16(a, b, c, 0, 0, 0);
}
__device__ __forceinline__ unsigned short f2b(float x){
  __hip_bfloat16 h = __float2bfloat16(x);
  return *reinterpret_cast<unsigned short*>(&h);
}
__device__ __forceinline__ float b2f(short u){
  unsigned int v = ((unsigned int)(unsigned short)u) << 16;
  return __uint_as_float(v);
}

#define GLOAD16(g, l) __builtin_amdgcn_global_load_lds( \
    (const __attribute__((address_space(1))) unsigned int*)(g), \
    (__attribute__((address_space(3))) unsigned int*)(l), 16, 0, 0)

__global__ void k_sentinel(float* out, float v){ out[threadIdx.x] = v; }

// fp32 -> bf16 weight conversion (4 mats of 512x512, contiguous out)
__global__ void k_cvt(const float* __restrict__ w0, const float* __restrict__ w1,
                      const float* __restrict__ w2, const float* __restrict__ w3,
                      unsigned short* __restrict__ out){
  int i = blockIdx.x*256 + threadIdx.x;   // f4 index; 4*65536 total
  int m = i >> 16;
  int r = i & 65535;
  const float* s = (m==0)?w0:((m==1)?w1:((m==2)?w2:w3));
  f4v v = ((const f4v*)s)[r];
  s4v o = { (short)f2b(v[0]), (short)f2b(v[1]), (short)f2b(v[2]), (short)f2b(v[3]) };
  ((s4v*)out)[i] = o;
}

// Transpose+cvt: X fp32 [slab][512][196] -> Xt bf16 [slab][196][512]
__global__ __launch_bounds__(256) void k_tr(const float* __restrict__ X,
                                            unsigned short* __restrict__ Xt){
  const int cc = blockIdx.x * 64;
  const int slab = blockIdx.y;
  const int tid = threadIdx.x;
  __shared__ unsigned short A[196][72];
  const int row = tid >> 2;
  const int j   = tid & 3;
  const float* src = X + (size_t)slab*(C_C*S_S) + (size_t)(cc+row)*S_S;
  for (int p = j; p < 49; p += 4){
    f4v v = *(const f4v*)(src + p*4);
    int s = p*4;
    A[s+0][row] = f2b(v[0]);
    A[s+1][row] = f2b(v[1]);
    A[s+2][row] = f2b(v[2]);
    A[s+3][row] = f2b(v[3]);
  }
  __syncthreads();
  unsigned short* dst = Xt + (size_t)slab*(S_S*C_C) + cc;
  for (int v = tid; v < S_S*8; v += 256){
    int s = v >> 3, c8 = v & 7;
    *(s8v*)(dst + (size_t)s*C_C + c8*8) = *(const s8v*)&A[s][c8*8];
  }
}

// LDS double-buffered projection GEMM (m97-style, T3 minimal 2-phase).
// Rows are globally contiguous: Xt [nrows][512]. Block = 128 rows x 128 cols
// of W1 (and, HASV, the same 128 cols of W2 -> transposed output).
// HASV grid: 3920 blocks (bijective XCD swizzle, 3920 = 8*490).
// outK[r][o] row-major (= [n][rn][o]); outVT[n][o][K_P] at col rn.
template<bool HASV>
__global__ __launch_bounds__(256) void k_projgemm(
    const unsigned short* __restrict__ Xt,
    const unsigned short* __restrict__ W1, const float* __restrict__ b1, const float* __restrict__ pos1,
    const unsigned short* __restrict__ W2, const float* __restrict__ b2, const float* __restrict__ pos2,
    unsigned short* __restrict__ outK, unsigned short* __restrict__ outVT)
{
  int id = blockIdx.x;
  int work = HASV ? ((id & 7)*490 + (id >> 3)) : id;
  const int ct = work & 3, rtile = work >> 2;
  const int r0 = rtile*128, cb = ct*128;
  const int tid = threadIdx.x, wid = tid>>6, lane = tid&63;
  const int lr = lane&15, lq = lane>>4;
  const int wr = wid>>1, wc = wid&1;

  __shared__ unsigned short SA[2][4096];          // [buf][granule(ch_grp*128+row)*8]
  __shared__ unsigned short SB[2][HASV?2:1][4096];

  f4v accK[4][4];
  f4v accV[HASV?4:1][HASV?4:1];
  #pragma unroll
  for (int i=0;i<4;i++)
    #pragma unroll
    for (int j=0;j<4;j++) accK[i][j]=(f4v){0,0,0,0};
  if (HASV){
    #pragma unroll
    for (int i=0;i<(HASV?4:1);i++)
      #pragma unroll
      for (int j=0;j<(HASV?4:1);j++) accV[i][j]=(f4v){0,0,0,0};
  }

  // stage one BK=32 slice into buf: wave w handles ch-group w (ch w*8..w*8+7)
  auto STAGE = [&](int buf, int c0){
    const unsigned short* ga = Xt + (size_t)(r0 + lane)*C_C + c0 + wid*8;
    GLOAD16(ga,             &SA[buf][wid*1024]);
    GLOAD16(ga + 64*C_C,    &SA[buf][wid*1024 + 512]);
    const unsigned short* gk = W1 + (size_t)(cb + lane)*C_C + c0 + wid*8;
    GLOAD16(gk,             &SB[buf][0][wid*1024]);
    GLOAD16(gk + 64*C_C,    &SB[buf][0][wid*1024 + 512]);
    if (HASV){
      const unsigned short* gv = W2 + (size_t)(cb + lane)*C_C + c0 + wid*8;
      GLOAD16(gv,           &SB[buf][HASV?1:0][wid*1024]);
      GLOAD16(gv + 64*C_C,  &SB[buf][HASV?1:0][wid*1024 + 512]);
    }
  };

  STAGE(0, 0);
  asm volatile("s_waitcnt vmcnt(0)" ::: "memory");
  __syncthreads();

  for (int it = 0; it < 16; ++it){
    const int buf = it & 1;
    if (it < 15) STAGE(buf^1, (it+1)*32);
    s8v af[4], bk[4];
    #pragma unroll
    for (int i=0;i<4;i++)
      af[i] = *(const s8v*)&SA[buf][lq*1024 + (wr*64 + i*16 + lr)*8];
    #pragma unroll
    for (int i=0;i<4;i++)
      bk[i] = *(const s8v*)&SB[buf][0][lq*1024 + (wc*64 + i*16 + lr)*8];
    #pragma unroll
    for (int ot=0;ot<4;ot++)
      #pragma unroll
      for (int rt=0;rt<4;rt++)
        accK[rt][ot] = mfma16(af[rt], bk[ot], accK[rt][ot]);
    if (HASV){
      s8v bv[4];
      #pragma unroll
      for (int i=0;i<4;i++)
        bv[i] = *(const s8v*)&SB[buf][HASV?1:0][lq*1024 + (wc*64 + i*16 + lr)*8];
      #pragma unroll
      for (int ot=0;ot<4;ot++)
        #pragma unroll
        for (int rt=0;rt<4;rt++)
          accV[ot][rt] = mfma16(bv[ot], af[rt], accV[ot][rt]);
    }
    asm volatile("s_waitcnt vmcnt(0)" ::: "memory");
    __syncthreads();
  }

  // K epilogue: C[r][o], row r = r0+wr*64+rt*16+lq*4+rr, col o = cb+wc*64+ot*16+lr
  #pragma unroll
  for (int ot=0;ot<4;ot++){
    const int o = cb + wc*64 + ot*16 + lr;
    const float bb = b1[o];
    #pragma unroll
    for (int rt=0;rt<4;rt++){
      #pragma unroll
      for (int rr=0;rr<4;rr++){
        const int r = r0 + wr*64 + rt*16 + lq*4 + rr;
        float bias = bb;
        if (HASV){
          int rn = r % K_K;
          bias += pos1[(rn/980)*C_C + o];
        }
        outK[(size_t)r*C_C + o] = f2b(accK[rt][ot][rr] + bias);
      }
    }
  }
  if (HASV){
    // V epilogue: C[o][r], o = cb+wc*64+ot*16+lq*4+rr, key-row r = r0+wr*64+rt*16+lr
    #pragma unroll
    for (int ot=0;ot<4;ot++){
      #pragma unroll
      for (int rr=0;rr<4;rr++){
        const int o = cb + wc*64 + ot*16 + lq*4 + rr;
        const float bb = b2[o];
        #pragma unroll
        for (int rt=0;rt<4;rt++){
          const int r = r0 + wr*64 + rt*16 + lr;
          const int n = r / K_K;
          const int rn = r - n*K_K;
          const float bias = bb + pos2[(rn/980)*C_C + o];
          outVT[(size_t)n*C_C*K_P + (size_t)o*K_P + rn] = f2b(accV[ot][rt][rr] + bias);
        }
      }
    }
  }
}

// QK^T: q [n][196][512], kf [n][3920][512] -> Sb bf16 [n][208][4096] (0 for k>=3920)
__global__ __launch_bounds__(256) void k_scores(
    const unsigned short* __restrict__ q, const unsigned short* __restrict__ kf,
    unsigned short* __restrict__ Sb)
{
  const int kb = blockIdx.x, sbk = blockIdx.y, n = blockIdx.z;
  const int tid=threadIdx.x, wid=tid>>6, lane=tid&63, lr=lane&15, lq=lane>>4;
  const int nt3 = 13 - sbk*3; const int nt = nt3 < 3 ? nt3 : 3;
  const int s0 = sbk*48;
  const unsigned short* qb = q + (size_t)n*S_S*C_C;
  const unsigned short* kbp = kf + (size_t)n*K_K*C_C;
  const int kcb = kb*256 + wid*64;
  f4v acc[3][4];
  #pragma unroll
  for (int i=0;i<3;i++)
    #pragma unroll
    for (int j=0;j<4;j++) acc[i][j]=(f4v){0,0,0,0};

  for (int c0=0;c0<C_C;c0+=32){
    s8v af[3];
    #pragma unroll
    for (int rt=0;rt<3;rt++)
      if (rt<nt) af[rt] = *(const s8v*)(qb + (size_t)(s0 + rt*16 + lr)*C_C + c0 + lq*8);
    #pragma unroll
    for (int ct=0;ct<4;ct++){
      s8v bfv = *(const s8v*)(kbp + (size_t)(kcb + ct*16 + lr)*C_C + c0 + lq*8);
      #pragma unroll
      for (int rt=0;rt<3;rt++) if (rt<nt) acc[rt][ct]=mfma16(af[rt],bfv,acc[rt][ct]);
    }
  }
  #pragma unroll
  for (int ct=0;ct<4;ct++){
    int kcol = kcb + ct*16 + lr;
    #pragma unroll
    for (int rt=0;rt<3;rt++) if (rt<nt){
      #pragma unroll
      for (int r=0;r<4;r++){
        int s = s0 + rt*16 + lq*4 + r;
        Sb[((size_t)n*S_P + s)*K_P + kcol] = (kcol < K_K) ? f2b(acc[rt][ct][r]) : (unsigned short)0;
      }
    }
  }
}

__global__ __launch_bounds__(256) void k_softmax(unsigned short* __restrict__ Sb){
  const int row = blockIdx.x;
  const int n = row / S_S, s = row - n*S_S;
  unsigned short* p = Sb + ((size_t)n*S_P + s)*K_P;
  const int tid = threadIdx.x;
  const bool valid = tid < 245;
  float x[16];
  if (valid){
    s8v v0 = *(const s8v*)(p + tid*16);
    s8v v1 = *(const s8v*)(p + tid*16 + 8);
    #pragma unroll
    for (int i=0;i<8;i++){ x[i]=b2f(v0[i]); x[8+i]=b2f(v1[i]); }
  } else {
    #pragma unroll
    for (int i=0;i<16;i++) x[i] = -1e30f;
  }
  float mx = x[0];
  #pragma unroll
  for (int i=1;i<16;i++) mx = fmaxf(mx, x[i]);
  #pragma unroll
  for (int d=32;d>=1;d>>=1) mx = fmaxf(mx, __shfl_xor(mx, d));
  __shared__ float red1[4], red2[4];
  if ((tid&63)==0) red1[tid>>6]=mx;
  __syncthreads();
  mx = fmaxf(fmaxf(red1[0],red1[1]),fmaxf(red1[2],red1[3]));
  float sum = 0.f;
  #pragma unroll
  for (int i=0;i<16;i++){ x[i]=__expf((x[i]-mx)*SCALEF); sum+=x[i]; }
  #pragma unroll
  for (int d=32;d>=1;d>>=1) sum += __shfl_xor(sum, d);
  if ((tid&63)==0) red2[tid>>6]=sum;
  __syncthreads();
  sum = red2[0]+red2[1]+red2[2]+red2[3];
  float inv = 1.f/sum;
  unsigned short o16[16];
  #pragma unroll
  for (int i=0;i<16;i++) o16[i] = f2b(x[i]*inv);
  if (valid){
    *(s8v*)(p + tid*16) = *(const s8v*)o16;
    *(s8v*)(p + tid*16 + 8) = *(const s8v*)(o16+8);
  }
}

__global__ __launch_bounds__(256) void k_pv(const unsigned short* __restrict__ Pb,
    const unsigned short* __restrict__ vt, float* __restrict__ O)
{
  const int cbk=blockIdx.x, sbk=blockIdx.y, n=blockIdx.z;
  const int tid=threadIdx.x, wid=tid>>6, lane=tid&63, lr=lane&15, lq=lane>>4;
  const int nt3 = 13 - sbk*3; const int nt = nt3 < 3 ? nt3 : 3;
  const int s0 = sbk*48;
  const unsigned short* pb = Pb + (size_t)n*S_P*K_P;
  const unsigned short* vb = vt + (size_t)n*C_C*K_P;
  const int ccb = cbk*256 + wid*64;
  f4v acc[3][4];
  #pragma unroll
  for (int i=0;i<3;i++)
    #pragma unroll
    for (int j=0;j<4;j++) acc[i][j]=(f4v){0,0,0,0};

  for (int k0=0;k0<K_P;k0+=32){
    s8v af[3];
    #pragma unroll
    for (int rt=0;rt<3;rt++)
      if (rt<nt) af[rt] = *(const s8v*)(pb + (size_t)(s0+rt*16+lr)*K_P + k0 + lq*8);
    #pragma unroll
    for (int ct=0;ct<4;ct++){
      s8v bfv = *(const s8v*)(vb + (size_t)(ccb+ct*16+lr)*K_P + k0 + lq*8);
      #pragma unroll
      for (int rt=0;rt<3;rt++) if (rt<nt) acc[rt][ct]=mfma16(af[rt],bfv,acc[rt][ct]);
    }
  }
  #pragma unroll
  for (int ct=0;ct<4;ct++){
    #pragma unroll
    for (int rt=0;rt<3;rt++) if (rt<nt){
      #pragma unroll
      for (int r=0;r<4;r++){
        int s = s0+rt*16+lq*4+r;
        O[((size_t)n*S_P + s)*C_C + ccb + ct*16 + lr] = acc[rt][ct][r];
      }
    }
  }
}

__global__ void k_lnpart(const float* __restrict__ O, float* __restrict__ sums){
  const int part = blockIdx.x, n = blockIdx.y;
  const int tid = threadIdx.x;
  const float* base = O + ((size_t)n*S_P + part*49)*C_C;
  float ls=0.f, ls2=0.f;
  for (int i = tid; i < 49*C_C/4; i += 256){
    f4v v = ((const f4v*)base)[i];
    ls  += v[0]+v[1]+v[2]+v[3];
    ls2 += v[0]*v[0]+v[1]*v[1]+v[2]*v[2]+v[3]*v[3];
  }
  #pragma unroll
  for (int d=32;d>=1;d>>=1){ ls += __shfl_xor(ls,d); ls2 += __shfl_xor(ls2,d); }
  __shared__ float r1[4], r2[4];
  if ((tid&63)==0){ r1[tid>>6]=ls; r2[tid>>6]=ls2; }
  __syncthreads();
  if (tid==0){
    atomicAdd(&sums[n*2],   r1[0]+r1[1]+r1[2]+r1[3]);
    atomicAdd(&sums[n*2+1], r2[0]+r2[1]+r2[2]+r2[3]);
  }
}

__global__ void k_norm(const float* __restrict__ O, const float* __restrict__ sums,
                       unsigned short* __restrict__ ob){
  size_t g = (size_t)blockIdx.x*256 + threadIdx.x;
  int n = (int)(g / (S_P*C_C/8));
  int rem = (int)(g - (size_t)n*(S_P*C_C/8));
  int s = rem / (C_C/8);
  const float inv = 1.f/((float)S_S*C_C);
  float mu = sums[n*2]*inv;
  float var = sums[n*2+1]*inv - mu*mu;
  float rq = rsqrtf(var + 1e-5f);
  const f4v* src = (const f4v*)(O + g*8);
  f4v a = src[0], b = src[1];
  unsigned short o16[8];
  if (s < S_S){
    #pragma unroll
    for (int i=0;i<4;i++){ float y=(a[i]-mu)*rq; o16[i]=f2b(fmaxf(y,0.f)); }
    #pragma unroll
    for (int i=0;i<4;i++){ float y=(b[i]-mu)*rq; o16[4+i]=f2b(fmaxf(y,0.f)); }
  } else {
    #pragma unroll
    for (int i=0;i<8;i++) o16[i]=0;
  }
  *(s8v*)(ob + g*8) = *(const s8v*)o16;
}

__global__ __launch_bounds__(256) void k_final(const unsigned short* __restrict__ ob,
    const unsigned short* __restrict__ Wo, const float* __restrict__ bo,
    const float* __restrict__ person, float* __restrict__ out)
{
  const int ocb = blockIdx.x, n = blockIdx.y;
  const int tid=threadIdx.x, wid=tid>>6, lane=tid&63, lr=lane&15, lq=lane>>4;
  const int ocb0 = ocb*64 + wid*16;
  const unsigned short* obp = ob + (size_t)n*S_P*C_C;
  f4v acc[13];
  #pragma unroll
  for (int i=0;i<13;i++) acc[i]=(f4v){0,0,0,0};
  for (int c0=0;c0<C_C;c0+=32){
    s8v af = *(const s8v*)(Wo + (size_t)(ocb0+lr)*C_C + c0 + lq*8);
    #pragma unroll
    for (int ct=0;ct<13;ct++){
      s8v bfv = *(const s8v*)(obp + (size_t)(ct*16+lr)*C_C + c0 + lq*8);
      acc[ct]=mfma16(af,bfv,acc[ct]);
    }
  }
  #pragma unroll
  for (int ct=0;ct<13;ct++){
    #pragma unroll
    for (int r=0;r<4;r++){
      int oc = ocb0 + lq*4 + r;
      int s = ct*16 + lr;
      if (s < S_S){
        size_t idx = ((size_t)n*C_C + oc)*S_S + s;
        out[idx] = acc[ct][r] + bo[oc] + person[idx];
      }
    }
  }
}

extern "C" void kernel_launch(void* const* d_in, const int* in_sizes, int n_in,
                              void* d_out, int out_size, void* d_ws, size_t ws_size,
                              hipStream_t stream)
{
  (void)in_sizes; (void)n_in; (void)out_size;
  const float* person = (const float*)d_in[0];
  const float* others = (const float*)d_in[1];
  const float* Wq = (const float*)d_in[2];
  const float* bq = (const float*)d_in[3];
  const float* Wk = (const float*)d_in[4];
  const float* bk = (const float*)d_in[5];
  const float* Wv = (const float*)d_in[6];
  const float* bv = (const float*)d_in[7];
  const float* Wo = (const float*)d_in[8];
  const float* bo = (const float*)d_in[9];
  const float* pos_k = (const float*)d_in[10];
  const float* pos_v = (const float*)d_in[11];
  float* out = (float*)d_out;

  char* ws = (char*)d_ws;
  size_t off = 0;
  auto alloc = [&](size_t bytes)->char*{
    char* p = ws + off; off += (bytes + 255) & ~(size_t)255; return p;
  };
  unsigned short* Wb  = (unsigned short*)alloc(4ull*C_C*C_C*2);
  unsigned short* Xt  = (unsigned short*)alloc(((size_t)N_B*M_O*S_S + 16)*C_C*2);
  unsigned short* Qt  = (unsigned short*)alloc(((size_t)N_B*S_S + 16)*C_C*2);
  unsigned short* qb  = (unsigned short*)alloc(((size_t)N_B*S_S + 16)*C_C*2);
  unsigned short* kfb = (unsigned short*)alloc(((size_t)N_B*K_K + 256)*C_C*2);
  unsigned short* vtb = (unsigned short*)alloc((size_t)N_B*C_C*K_P*2);
  float* sums         = (float*)alloc(2*N_B*sizeof(float));

  // alias dead Xt region for post-projection buffers
  size_t aoff = 0;
  auto alias = [&](size_t bytes)->char*{
    char* p = (char*)Xt + aoff; aoff += (bytes + 255) & ~(size_t)255; return p;
  };
  unsigned short* Sbuf = (unsigned short*)alias((size_t)N_B*S_P*K_P*2);
  float* Obuf          = (float*)alias((size_t)N_B*S_P*C_C*4);
  unsigned short* obb  = (unsigned short*)alias((size_t)N_B*S_P*C_C*2);

  if (off > ws_size) {
    k_sentinel<<<1,256,0,stream>>>(out, (float)(ws_size>>20));
    return;
  }

  hipMemsetAsync(sums, 0, 2*N_B*sizeof(float), stream);
  k_cvt<<<1024,256,0,stream>>>(Wq,Wk,Wv,Wo,Wb);
  k_tr<<<dim3(8,N_B*M_O),256,0,stream>>>(others, Xt);
  k_tr<<<dim3(8,N_B),256,0,stream>>>(person, Qt);
  k_projgemm<true ><<<3920,256,0,stream>>>(Xt,
      Wb + 262144, bk, pos_k, Wb + 2*262144, bv, pos_v, kfb, vtb);
  k_projgemm<false><<<196,256,0,stream>>>(Qt,
      Wb, bq, nullptr, nullptr, nullptr, nullptr, qb, nullptr);
  k_scores<<<dim3(16,5,N_B),256,0,stream>>>(qb, kfb, Sbuf);
  k_softmax<<<N_B*S_S,256,0,stream>>>(Sbuf);
  k_pv<<<dim3(2,5,N_B),256,0,stream>>>(Sbuf, vtb, Obuf);
  k_lnpart<<<dim3(4,N_B),256,0,stream>>>(Obuf, sums);
  k_norm<<<1664,256,0,stream>>>(Obuf, sums, obb);
  k_final<<<dim3(8,N_B),256,0,stream>>>(obb, Wb + 3*262144, bo, person, out);
}

// Round 4
// 1056.990 us; speedup vs baseline: 1.5452x; 1.0319x over previous
//
#include <hip/hip_runtime.h>
#include <hip/hip_bf16.h>

#define N_B 32
#define M_O 20
#define C_C 512
#define S_S 196
#define S_P 208
#define K_K 3920
#define K_P 4096
#define P_G 5
#define SCALEF 0.044194173824159216f  // 1/sqrt(512)

typedef short s4v __attribute__((ext_vector_type(4)));
typedef short s8v __attribute__((ext_vector_type(8)));
typedef float f4v __attribute__((ext_vector_type(4)));

__device__ __forceinline__ f4v mfma16(s8v a, s8v b, f4v c){
  return __builtin_amdgcn_mfma_f32_16x16x32_bf16(a, b, c, 0, 0, 0);
}
__device__ __forceinline__ unsigned short f2b(float x){
  __hip_bfloat16 h = __float2bfloat16(x);
  return *reinterpret_cast<unsigned short*>(&h);
}
__device__ __forceinline__ float b2f(short u){
  unsigned int v = ((unsigned int)(unsigned short)u) << 16;
  return __uint_as_float(v);
}

#define GLOAD16(g, l) __builtin_amdgcn_global_load_lds( \
    (const __attribute__((address_space(1))) unsigned int*)(g), \
    (__attribute__((address_space(3))) unsigned int*)(l), 16, 0, 0)

__global__ void k_sentinel(float* out, float v){ out[threadIdx.x] = v; }

// fp32 -> bf16 weight conversion (4 mats of 512x512, contiguous out)
__global__ void k_cvt(const float* __restrict__ w0, const float* __restrict__ w1,
                      const float* __restrict__ w2, const float* __restrict__ w3,
                      unsigned short* __restrict__ out){
  int i = blockIdx.x*256 + threadIdx.x;   // f4 index; 4*65536 total
  int m = i >> 16;
  int r = i & 65535;
  const float* s = (m==0)?w0:((m==1)?w1:((m==2)?w2:w3));
  f4v v = ((const f4v*)s)[r];
  s4v o = { (short)f2b(v[0]), (short)f2b(v[1]), (short)f2b(v[2]), (short)f2b(v[3]) };
  ((s4v*)out)[i] = o;
}

// Transpose+cvt: X fp32 [slab][512][196] -> Xt bf16 [slab][196][512]
__global__ __launch_bounds__(256) void k_tr(const float* __restrict__ X,
                                            unsigned short* __restrict__ Xt){
  const int cc = blockIdx.x * 64;
  const int slab = blockIdx.y;
  const int tid = threadIdx.x;
  __shared__ unsigned short A[196][72];
  const int row = tid >> 2;
  const int j   = tid & 3;
  const float* src = X + (size_t)slab*(C_C*S_S) + (size_t)(cc+row)*S_S;
  for (int p = j; p < 49; p += 4){
    f4v v = *(const f4v*)(src + p*4);
    int s = p*4;
    A[s+0][row] = f2b(v[0]);
    A[s+1][row] = f2b(v[1]);
    A[s+2][row] = f2b(v[2]);
    A[s+3][row] = f2b(v[3]);
  }
  __syncthreads();
  unsigned short* dst = Xt + (size_t)slab*(S_S*C_C) + cc;
  for (int v = tid; v < S_S*8; v += 256){
    int s = v >> 3, c8 = v & 7;
    *(s8v*)(dst + (size_t)s*C_C + c8*8) = *(const s8v*)&A[s][c8*8];
  }
}

// LDS double-buffered projection GEMM, 64 acc regs/wave for 3 waves/SIMD.
// Block = 64 rows x {128 K-cols + 128 V-cols} (HASV) or 64 x 256 W1-cols.
// Waves 0-1: K output (64x64 each); waves 2-3: V output, swapped-operand MFMA
// -> acc holds C^T, store to outVT coalesced.
// HASV grid: 7840 = 8*980 blocks, bijective XCD swizzle.
template<bool HASV>
__global__ __launch_bounds__(256, 3) void k_projgemm(
    const unsigned short* __restrict__ Xt,
    const unsigned short* __restrict__ W1, const float* __restrict__ b1, const float* __restrict__ pos1,
    const unsigned short* __restrict__ W2, const float* __restrict__ b2, const float* __restrict__ pos2,
    unsigned short* __restrict__ outK, unsigned short* __restrict__ outVT)
{
  const int id = blockIdx.x;
  const int work = HASV ? ((id & 7)*980 + (id >> 3)) : id;
  const int ct    = HASV ? (work & 3) : (work & 1);
  const int rtile = HASV ? (work >> 2) : (work >> 1);
  const int r0 = rtile*64;
  const int cb = ct * (HASV ? 128 : 256);
  const int tid = threadIdx.x, wid = tid>>6, lane = tid&63;
  const int lr = lane&15, lq = lane>>4;
  const int mat = wid >> 1, chalf = (wid & 1)*64;
  const bool isV = HASV && (mat == 1);

  const unsigned short* WB = HASV ? W2 : W1;
  const int cbB = HASV ? cb : cb + 128;

  __shared__ unsigned short SA[2][2048];      // [buf][(cg*64+row)*8]
  __shared__ unsigned short SB[2][2][4096];   // [buf][mat][(cg*128+col)*8]

  f4v acc[4][4];
  #pragma unroll
  for (int i=0;i<4;i++)
    #pragma unroll
    for (int j=0;j<4;j++) acc[i][j]=(f4v){0,0,0,0};

  auto STAGE = [&](int buf, int c0){
    const unsigned short* ga = Xt + (size_t)(r0 + lane)*C_C + c0 + wid*8;
    GLOAD16(ga, &SA[buf][wid*512]);
    const unsigned short* g1 = W1 + (size_t)(cb + lane)*C_C + c0 + wid*8;
    GLOAD16(g1,           &SB[buf][0][wid*1024]);
    GLOAD16(g1 + 64*C_C,  &SB[buf][0][wid*1024 + 512]);
    const unsigned short* g2 = WB + (size_t)(cbB + lane)*C_C + c0 + wid*8;
    GLOAD16(g2,           &SB[buf][1][wid*1024]);
    GLOAD16(g2 + 64*C_C,  &SB[buf][1][wid*1024 + 512]);
  };

  STAGE(0, 0);
  asm volatile("s_waitcnt vmcnt(0)" ::: "memory");
  __syncthreads();

  for (int it = 0; it < 16; ++it){
    const int buf = it & 1;
    if (it < 15) STAGE(buf^1, (it+1)*32);
    s8v af[4], bf[4];
    #pragma unroll
    for (int i=0;i<4;i++)
      af[i] = *(const s8v*)&SA[buf][lq*512 + (i*16 + lr)*8];
    #pragma unroll
    for (int i=0;i<4;i++)
      bf[i] = *(const s8v*)&SB[buf][mat][lq*1024 + (chalf + i*16 + lr)*8];
    if (!isV){
      #pragma unroll
      for (int ot=0;ot<4;ot++)
        #pragma unroll
        for (int rt=0;rt<4;rt++)
          acc[rt][ot] = mfma16(af[rt], bf[ot], acc[rt][ot]);
    } else {
      #pragma unroll
      for (int ot=0;ot<4;ot++)
        #pragma unroll
        for (int rt=0;rt<4;rt++)
          acc[ot][rt] = mfma16(bf[ot], af[rt], acc[ot][rt]);
    }
    asm volatile("s_waitcnt vmcnt(0)" ::: "memory");
    __syncthreads();
  }

  const int cout = HASV ? (cb + chalf) : (cb + mat*128 + chalf);
  if (!isV){
    // C[r][o]: r = r0 + rt*16 + lq*4 + rr, o = cout + ot*16 + lr
    #pragma unroll
    for (int ot=0;ot<4;ot++){
      const int o = cout + ot*16 + lr;
      const float bb = b1[o];
      #pragma unroll
      for (int rt=0;rt<4;rt++){
        #pragma unroll
        for (int rr=0;rr<4;rr++){
          const int r = r0 + rt*16 + lq*4 + rr;
          float bias = bb;
          if (HASV) bias += pos1[((r % K_K)/980)*C_C + o];
          outK[(size_t)r*C_C + o] = f2b(acc[rt][ot][rr] + bias);
        }
      }
    }
  } else {
    // C^T[o][r]: o = cout + ot*16 + lq*4 + rr, key-row r = r0 + rt*16 + lr
    #pragma unroll
    for (int ot=0;ot<4;ot++){
      #pragma unroll
      for (int rr=0;rr<4;rr++){
        const int o = cout + ot*16 + lq*4 + rr;
        const float bb = b2[o];
        #pragma unroll
        for (int rt=0;rt<4;rt++){
          const int r = r0 + rt*16 + lr;
          const int n = r / K_K;
          const int rn = r - n*K_K;
          const float bias = bb + pos2[(rn/980)*C_C + o];
          outVT[(size_t)n*C_C*K_P + (size_t)o*K_P + rn] = f2b(acc[ot][rt][rr] + bias);
        }
      }
    }
  }
}

// QK^T: q [n][196][512], kf [n][3920][512] -> Sb bf16 [n][208][4096] (0 for k>=3920)
__global__ __launch_bounds__(256) void k_scores(
    const unsigned short* __restrict__ q, const unsigned short* __restrict__ kf,
    unsigned short* __restrict__ Sb)
{
  const int kb = blockIdx.x, sbk = blockIdx.y, n = blockIdx.z;
  const int tid=threadIdx.x, wid=tid>>6, lane=tid&63, lr=lane&15, lq=lane>>4;
  const int nt3 = 13 - sbk*3; const int nt = nt3 < 3 ? nt3 : 3;
  const int s0 = sbk*48;
  const unsigned short* qb = q + (size_t)n*S_S*C_C;
  const unsigned short* kbp = kf + (size_t)n*K_K*C_C;
  const int kcb = kb*256 + wid*64;
  f4v acc[3][4];
  #pragma unroll
  for (int i=0;i<3;i++)
    #pragma unroll
    for (int j=0;j<4;j++) acc[i][j]=(f4v){0,0,0,0};

  for (int c0=0;c0<C_C;c0+=32){
    s8v af[3];
    #pragma unroll
    for (int rt=0;rt<3;rt++)
      if (rt<nt) af[rt] = *(const s8v*)(qb + (size_t)(s0 + rt*16 + lr)*C_C + c0 + lq*8);
    #pragma unroll
    for (int ct=0;ct<4;ct++){
      s8v bfv = *(const s8v*)(kbp + (size_t)(kcb + ct*16 + lr)*C_C + c0 + lq*8);
      #pragma unroll
      for (int rt=0;rt<3;rt++) if (rt<nt) acc[rt][ct]=mfma16(af[rt],bfv,acc[rt][ct]);
    }
  }
  #pragma unroll
  for (int ct=0;ct<4;ct++){
    int kcol = kcb + ct*16 + lr;
    #pragma unroll
    for (int rt=0;rt<3;rt++) if (rt<nt){
      #pragma unroll
      for (int r=0;r<4;r++){
        int s = s0 + rt*16 + lq*4 + r;
        Sb[((size_t)n*S_P + s)*K_P + kcol] = (kcol < K_K) ? f2b(acc[rt][ct][r]) : (unsigned short)0;
      }
    }
  }
}

__global__ __launch_bounds__(256) void k_softmax(unsigned short* __restrict__ Sb){
  const int row = blockIdx.x;
  const int n = row / S_S, s = row - n*S_S;
  unsigned short* p = Sb + ((size_t)n*S_P + s)*K_P;
  const int tid = threadIdx.x;
  const bool valid = tid < 245;
  float x[16];
  if (valid){
    s8v v0 = *(const s8v*)(p + tid*16);
    s8v v1 = *(const s8v*)(p + tid*16 + 8);
    #pragma unroll
    for (int i=0;i<8;i++){ x[i]=b2f(v0[i]); x[8+i]=b2f(v1[i]); }
  } else {
    #pragma unroll
    for (int i=0;i<16;i++) x[i] = -1e30f;
  }
  float mx = x[0];
  #pragma unroll
  for (int i=1;i<16;i++) mx = fmaxf(mx, x[i]);
  #pragma unroll
  for (int d=32;d>=1;d>>=1) mx = fmaxf(mx, __shfl_xor(mx, d));
  __shared__ float red1[4], red2[4];
  if ((tid&63)==0) red1[tid>>6]=mx;
  __syncthreads();
  mx = fmaxf(fmaxf(red1[0],red1[1]),fmaxf(red1[2],red1[3]));
  float sum = 0.f;
  #pragma unroll
  for (int i=0;i<16;i++){ x[i]=__expf((x[i]-mx)*SCALEF); sum+=x[i]; }
  #pragma unroll
  for (int d=32;d>=1;d>>=1) sum += __shfl_xor(sum, d);
  if ((tid&63)==0) red2[tid>>6]=sum;
  __syncthreads();
  sum = red2[0]+red2[1]+red2[2]+red2[3];
  float inv = 1.f/sum;
  unsigned short o16[16];
  #pragma unroll
  for (int i=0;i<16;i++) o16[i] = f2b(x[i]*inv);
  if (valid){
    *(s8v*)(p + tid*16) = *(const s8v*)o16;
    *(s8v*)(p + tid*16 + 8) = *(const s8v*)(o16+8);
  }
}

__global__ __launch_bounds__(256) void k_pv(const unsigned short* __restrict__ Pb,
    const unsigned short* __restrict__ vt, float* __restrict__ O)
{
  const int cbk=blockIdx.x, sbk=blockIdx.y, n=blockIdx.z;
  const int tid=threadIdx.x, wid=tid>>6, lane=tid&63, lr=lane&15, lq=lane>>4;
  const int nt3 = 13 - sbk*3; const int nt = nt3 < 3 ? nt3 : 3;
  const int s0 = sbk*48;
  const unsigned short* pb = Pb + (size_t)n*S_P*K_P;
  const unsigned short* vb = vt + (size_t)n*C_C*K_P;
  const int ccb = cbk*256 + wid*64;
  f4v acc[3][4];
  #pragma unroll
  for (int i=0;i<3;i++)
    #pragma unroll
    for (int j=0;j<4;j++) acc[i][j]=(f4v){0,0,0,0};

  for (int k0=0;k0<K_P;k0+=32){
    s8v af[3];
    #pragma unroll
    for (int rt=0;rt<3;rt++)
      if (rt<nt) af[rt] = *(const s8v*)(pb + (size_t)(s0+rt*16+lr)*K_P + k0 + lq*8);
    #pragma unroll
    for (int ct=0;ct<4;ct++){
      s8v bfv = *(const s8v*)(vb + (size_t)(ccb+ct*16+lr)*K_P + k0 + lq*8);
      #pragma unroll
      for (int rt=0;rt<3;rt++) if (rt<nt) acc[rt][ct]=mfma16(af[rt],bfv,acc[rt][ct]);
    }
  }
  #pragma unroll
  for (int ct=0;ct<4;ct++){
    #pragma unroll
    for (int rt=0;rt<3;rt++) if (rt<nt){
      #pragma unroll
      for (int r=0;r<4;r++){
        int s = s0+rt*16+lq*4+r;
        O[((size_t)n*S_P + s)*C_C + ccb + ct*16 + lr] = acc[rt][ct][r];
      }
    }
  }
}

__global__ void k_lnpart(const float* __restrict__ O, float* __restrict__ sums){
  const int part = blockIdx.x, n = blockIdx.y;
  const int tid = threadIdx.x;
  const float* base = O + ((size_t)n*S_P + part*49)*C_C;
  float ls=0.f, ls2=0.f;
  for (int i = tid; i < 49*C_C/4; i += 256){
    f4v v = ((const f4v*)base)[i];
    ls  += v[0]+v[1]+v[2]+v[3];
    ls2 += v[0]*v[0]+v[1]*v[1]+v[2]*v[2]+v[3]*v[3];
  }
  #pragma unroll
  for (int d=32;d>=1;d>>=1){ ls += __shfl_xor(ls,d); ls2 += __shfl_xor(ls2,d); }
  __shared__ float r1[4], r2[4];
  if ((tid&63)==0){ r1[tid>>6]=ls; r2[tid>>6]=ls2; }
  __syncthreads();
  if (tid==0){
    atomicAdd(&sums[n*2],   r1[0]+r1[1]+r1[2]+r1[3]);
    atomicAdd(&sums[n*2+1], r2[0]+r2[1]+r2[2]+r2[3]);
  }
}

__global__ void k_norm(const float* __restrict__ O, const float* __restrict__ sums,
                       unsigned short* __restrict__ ob){
  size_t g = (size_t)blockIdx.x*256 + threadIdx.x;
  int n = (int)(g / (S_P*C_C/8));
  int rem = (int)(g - (size_t)n*(S_P*C_C/8));
  int s = rem / (C_C/8);
  const float inv = 1.f/((float)S_S*C_C);
  float mu = sums[n*2]*inv;
  float var = sums[n*2+1]*inv - mu*mu;
  float rq = rsqrtf(var + 1e-5f);
  const f4v* src = (const f4v*)(O + g*8);
  f4v a = src[0], b = src[1];
  unsigned short o16[8];
  if (s < S_S){
    #pragma unroll
    for (int i=0;i<4;i++){ float y=(a[i]-mu)*rq; o16[i]=f2b(fmaxf(y,0.f)); }
    #pragma unroll
    for (int i=0;i<4;i++){ float y=(b[i]-mu)*rq; o16[4+i]=f2b(fmaxf(y,0.f)); }
  } else {
    #pragma unroll
    for (int i=0;i<8;i++) o16[i]=0;
  }
  *(s8v*)(ob + g*8) = *(const s8v*)o16;
}

__global__ __launch_bounds__(256) void k_final(const unsigned short* __restrict__ ob,
    const unsigned short* __restrict__ Wo, const float* __restrict__ bo,
    const float* __restrict__ person, float* __restrict__ out)
{
  const int ocb = blockIdx.x, n = blockIdx.y;
  const int tid=threadIdx.x, wid=tid>>6, lane=tid&63, lr=lane&15, lq=lane>>4;
  const int ocb0 = ocb*64 + wid*16;
  const unsigned short* obp = ob + (size_t)n*S_P*C_C;
  f4v acc[13];
  #pragma unroll
  for (int i=0;i<13;i++) acc[i]=(f4v){0,0,0,0};
  for (int c0=0;c0<C_C;c0+=32){
    s8v af = *(const s8v*)(Wo + (size_t)(ocb0+lr)*C_C + c0 + lq*8);
    #pragma unroll
    for (int ct=0;ct<13;ct++){
      s8v bfv = *(const s8v*)(obp + (size_t)(ct*16+lr)*C_C + c0 + lq*8);
      acc[ct]=mfma16(af,bfv,acc[ct]);
    }
  }
  #pragma unroll
  for (int ct=0;ct<13;ct++){
    #pragma unroll
    for (int r=0;r<4;r++){
      int oc = ocb0 + lq*4 + r;
      int s = ct*16 + lr;
      if (s < S_S){
        size_t idx = ((size_t)n*C_C + oc)*S_S + s;
        out[idx] = acc[ct][r] + bo[oc] + person[idx];
      }
    }
  }
}

extern "C" void kernel_launch(void* const* d_in, const int* in_sizes, int n_in,
                              void* d_out, int out_size, void* d_ws, size_t ws_size,
                              hipStream_t stream)
{
  (void)in_sizes; (void)n_in; (void)out_size;
  const float* person = (const float*)d_in[0];
  const float* others = (const float*)d_in[1];
  const float* Wq = (const float*)d_in[2];
  const float* bq = (const float*)d_in[3];
  const float* Wk = (const float*)d_in[4];
  const float* bk = (const float*)d_in[5];
  const float* Wv = (const float*)d_in[6];
  const float* bv = (const float*)d_in[7];
  const float* Wo = (const float*)d_in[8];
  const float* bo = (const float*)d_in[9];
  const float* pos_k = (const float*)d_in[10];
  const float* pos_v = (const float*)d_in[11];
  float* out = (float*)d_out;

  char* ws = (char*)d_ws;
  size_t off = 0;
  auto alloc = [&](size_t bytes)->char*{
    char* p = ws + off; off += (bytes + 255) & ~(size_t)255; return p;
  };
  unsigned short* Wb  = (unsigned short*)alloc(4ull*C_C*C_C*2);
  unsigned short* Xt  = (unsigned short*)alloc(((size_t)N_B*M_O*S_S + 16)*C_C*2);
  unsigned short* Qt  = (unsigned short*)alloc(((size_t)N_B*S_S + 16)*C_C*2);
  unsigned short* qb  = (unsigned short*)alloc(((size_t)N_B*S_S + 16)*C_C*2);
  unsigned short* kfb = (unsigned short*)alloc(((size_t)N_B*K_K + 256)*C_C*2);
  unsigned short* vtb = (unsigned short*)alloc((size_t)N_B*C_C*K_P*2);
  float* sums         = (float*)alloc(2*N_B*sizeof(float));

  // alias dead Xt region for post-projection buffers
  size_t aoff = 0;
  auto alias = [&](size_t bytes)->char*{
    char* p = (char*)Xt + aoff; aoff += (bytes + 255) & ~(size_t)255; return p;
  };
  unsigned short* Sbuf = (unsigned short*)alias((size_t)N_B*S_P*K_P*2);
  float* Obuf          = (float*)alias((size_t)N_B*S_P*C_C*4);
  unsigned short* obb  = (unsigned short*)alias((size_t)N_B*S_P*C_C*2);

  if (off > ws_size) {
    k_sentinel<<<1,256,0,stream>>>(out, (float)(ws_size>>20));
    return;
  }

  hipMemsetAsync(sums, 0, 2*N_B*sizeof(float), stream);
  k_cvt<<<1024,256,0,stream>>>(Wq,Wk,Wv,Wo,Wb);
  k_tr<<<dim3(8,N_B*M_O),256,0,stream>>>(others, Xt);
  k_tr<<<dim3(8,N_B),256,0,stream>>>(person, Qt);
  k_projgemm<true ><<<7840,256,0,stream>>>(Xt,
      Wb + 262144, bk, pos_k, Wb + 2*262144, bv, pos_v, kfb, vtb);
  k_projgemm<false><<<196,256,0,stream>>>(Qt,
      Wb, bq, nullptr, nullptr, nullptr, nullptr, qb, nullptr);
  k_scores<<<dim3(16,5,N_B),256,0,stream>>>(qb, kfb, Sbuf);
  k_softmax<<<N_B*S_S,256,0,stream>>>(Sbuf);
  k_pv<<<dim3(2,5,N_B),256,0,stream>>>(Sbuf, vtb, Obuf);
  k_lnpart<<<dim3(4,N_B),256,0,stream>>>(Obuf, sums);
  k_norm<<<1664,256,0,stream>>>(Obuf, sums, obb);
  k_final<<<dim3(8,N_B),256,0,stream>>>(obb, Wb + 3*262144, bo, person, out);
}